// Round 3
// baseline (65.937 us; speedup 1.0000x reference)
//
#include <hip/hip_runtime.h>

// loss = sum_c S2[c] / (sqrt(S1[c]) + 1e-4)
//   S1[c] = sum_i abu[i,c]^2
//   S2[c] = sum_i | stencil(abu)[i,c] * abu[i,c] |
// stencil = (4 straight + 4 diag/sqrt2) / (4/sqrt2 + 4), zero-padded 3x3.
//
// Single-node design (launch-overhead-bound problem): 40 blocks compute
// per-block partials, publish to d_ws slots + MAGIC flag (device-scope
// atomics, cross-XCD coherent), block 0 spin-waits and finalizes.
// No d_ws zero-init required: slots are written, not accumulated; flags
// only need initial != MAGIC (harness poisons 0xAAAAAAAA).

#define HH 100
#define WW 100
#define CC 9
#define NPIX (HH * WW)
#define NBLK 40
#define NPART (2 * CC)          // 18 partials per block
#define MAGIC 0x5A5A5A5Au

__global__ __launch_bounds__(256) void k_fused(const float* __restrict__ abu,
                                               float* __restrict__ out,
                                               float* __restrict__ ws) {
    const float INV_SQRT2 = 0.70710678118654752440f;
    const float INV_DENOM = 1.0f / 6.82842712474619009760f;  // 1/(4/sqrt2+4)

    const int p = blockIdx.x * blockDim.x + threadIdx.x;

    float sq[CC];
    float pr[CC];

    if (p < NPIX) {
        const int h = p / WW;
        const int w = p - h * WW;
        const int base = p * CC;
        const bool up = (h > 0), dn = (h < HH - 1);
        const bool lf = (w > 0), rt = (w < WW - 1);
        const int oU = -WW * CC, oD = WW * CC, oL = -CC, oR = CC;

#pragma unroll
        for (int c = 0; c < CC; ++c) {
            float s = 0.0f;
            float d = 0.0f;
            if (up) s += abu[base + oU + c];
            if (dn) s += abu[base + oD + c];
            if (lf) s += abu[base + oL + c];
            if (rt) s += abu[base + oR + c];
            if (up && lf) d += abu[base + oU + oL + c];
            if (up && rt) d += abu[base + oU + oR + c];
            if (dn && lf) d += abu[base + oD + oL + c];
            if (dn && rt) d += abu[base + oD + oR + c];
            float st = (s + d * INV_SQRT2) * INV_DENOM;
            float cen = abu[base + c];
            sq[c] = cen * cen;
            pr[c] = fabsf(st * cen);
        }
    } else {
#pragma unroll
        for (int c = 0; c < CC; ++c) { sq[c] = 0.0f; pr[c] = 0.0f; }
    }

    __shared__ float part[NPART];
    if (threadIdx.x < NPART) part[threadIdx.x] = 0.0f;
    __syncthreads();

    // Wave (64-lane) butterfly reduce per channel, then one LDS atomic/wave.
#pragma unroll
    for (int c = 0; c < CC; ++c) {
        float a = sq[c];
        float b = pr[c];
#pragma unroll
        for (int off = 32; off > 0; off >>= 1) {
            a += __shfl_down(a, off);
            b += __shfl_down(b, off);
        }
        if ((threadIdx.x & 63) == 0) {
            atomicAdd(&part[c], a);
            atomicAdd(&part[CC + c], b);
        }
    }
    __syncthreads();

    // Publish this block's 18 partials (device-scope atomic stores), then flag.
    if (threadIdx.x < NPART)
        atomicExch(&ws[blockIdx.x * NPART + threadIdx.x], part[threadIdx.x]);
    __threadfence();  // release: partials visible before flag
    unsigned* flags = (unsigned*)(ws + 768);  // 768 >= NBLK*NPART, aligned
    if (threadIdx.x == 0) atomicExch(&flags[blockIdx.x], MAGIC);

    if (blockIdx.x != 0) return;

    // ---- block 0: wait for all 40 flags, then finalize ----
    __shared__ float acc[NPART];
    if (threadIdx.x < NPART) acc[threadIdx.x] = 0.0f;

    if (threadIdx.x < NBLK) {
        // one lane per flag; wave re-converges when every lane's flag is set
        while (atomicAdd(&flags[threadIdx.x], 0u) != MAGIC) {
            __builtin_amdgcn_s_sleep(1);
        }
    }
    __syncthreads();
    __threadfence();  // acquire side

    for (int s = (int)threadIdx.x; s < NBLK * NPART; s += 256) {
        float v = atomicAdd(&ws[s], 0.0f);  // device-coherent read
        int c = s - (s / NPART) * NPART;    // s % 18
        atomicAdd(&acc[c], v);
    }
    __syncthreads();

    float v = 0.0f;
    if (threadIdx.x < CC)
        v = acc[CC + threadIdx.x] / (sqrtf(acc[threadIdx.x]) + 1e-4f);
#pragma unroll
    for (int off = 8; off > 0; off >>= 1) v += __shfl_down(v, off);
    if (threadIdx.x == 0) out[0] = v;
}

extern "C" void kernel_launch(void* const* d_in, const int* in_sizes, int n_in,
                              void* d_out, int out_size, void* d_ws, size_t ws_size,
                              hipStream_t stream) {
    const float* abu = (const float*)d_in[0];
    float* out = (float*)d_out;
    float* ws = (float*)d_ws;

    k_fused<<<NBLK, 256, 0, stream>>>(abu, out, ws);
}